// Round 7
// baseline (2111.243 us; speedup 1.0000x reference)
//
#include <hip/hip_runtime.h>

// SineLSTM: 2-layer LSTM (H=50), B=512 rows, one row per block.
// R9 = R8 with the gate-gather bug fixed (ds_bpermute under a value-ternary
// can be emitted exec-masked -> inactive source lanes -> garbage; absmax
// 0.277). Gates are now gathered DIRECTLY from the LDS gate buffer at
// gl[ln], gl[50+ln], gl[100+ln], gl[150+ln] (per-lane consecutive addrs,
// 2-way bank aliasing = free). No cross-lane intrinsics in the U-phases.
//
// Structure (from R8): TB=128 (2 waves), thread t owns gate-rows t and
// t+128 (300 weight VGPRs, launch_bounds(128,1) -> 1 wave/SIMD). Unit u's
// h/c state lives in lane u's registers, redundantly in both waves. Dots
// consume h via CHUNKED readlane: 8 readlane -> 8 SGPRs -> 16 FMAs (2 rows),
// so zero h-broadcast LDS traffic (R2/R5/R6's wall: ~312 b128 broadcasts/
// CU-step ~ 3744cy = measured step time; broadcasts don't dedupe).
// Only 200 gate values cross waves per G-phase. 2 barriers/step.
// FP order bit-identical to R5: per-acc k-sequences 0,4,..48 / 1,5,..49 /
// 2,6,..46 / 3,7,..47; combine (a0+a2)+(a1+a3); G2 = b2 + wi2-sweep +
// wh2-sweep; same activations; same output reduce tree.

#define Hh   50
#define TLEN 1024

__device__ __forceinline__ float fast_sigmoid(float v) {
    return 1.0f / (1.0f + __expf(-v));
}
__device__ __forceinline__ float fast_tanh(float v) {
    return 1.0f - 2.0f / (__expf(2.0f * v) + 1.0f);
}
__device__ __forceinline__ float rl(float v, int k) {   // lane k -> SGPR (wave-uniform)
    return __int_as_float(__builtin_amdgcn_readlane(__float_as_int(v), k));
}

// 8-wide dot chunk: ascending k, accumulator = k&3 (R5's exact FP order).
#define CHUNK8(WA, WB, HSP, C) do {                                          \
    float s0 = rl(HSP,(C)+0), s1 = rl(HSP,(C)+1), s2 = rl(HSP,(C)+2),        \
          s3 = rl(HSP,(C)+3), s4 = rl(HSP,(C)+4), s5 = rl(HSP,(C)+5),        \
          s6 = rl(HSP,(C)+6), s7 = rl(HSP,(C)+7);                            \
    aA0 += WA[(C)+0]*s0; aA1 += WA[(C)+1]*s1; aA2 += WA[(C)+2]*s2;           \
    aA3 += WA[(C)+3]*s3; aA0 += WA[(C)+4]*s4; aA1 += WA[(C)+5]*s5;           \
    aA2 += WA[(C)+6]*s6; aA3 += WA[(C)+7]*s7;                                \
    aB0 += WB[(C)+0]*s0; aB1 += WB[(C)+1]*s1; aB2 += WB[(C)+2]*s2;           \
    aB3 += WB[(C)+3]*s3; aB0 += WB[(C)+4]*s4; aB1 += WB[(C)+5]*s5;           \
    aB2 += WB[(C)+6]*s6; aB3 += WB[(C)+7]*s7;                                \
} while (0)
#define CHUNK2T(WA, WB, HSP) do {        /* tail k=48,49 (R5: a0,a1) */      \
    float s0 = rl(HSP,48), s1 = rl(HSP,49);                                  \
    aA0 += WA[48]*s0; aA1 += WA[49]*s1;                                      \
    aB0 += WB[48]*s0; aB1 += WB[49]*s1;                                      \
} while (0)

extern "C" __global__ __launch_bounds__(128, 1)
void sine_lstm_kernel(const float* __restrict__ x,
                      const float* __restrict__ W_ih1,
                      const float* __restrict__ W_hh1,
                      const float* __restrict__ b_ih1,
                      const float* __restrict__ b_hh1,
                      const float* __restrict__ W_ih2,
                      const float* __restrict__ W_hh2,
                      const float* __restrict__ b_ih2,
                      const float* __restrict__ b_hh2,
                      const float* __restrict__ W_lin,
                      const float* __restrict__ b_lin,
                      const int*   __restrict__ predict_p,
                      float* __restrict__ out,
                      int T)
{
    __shared__ __align__(16) float x_lds[TLEN];
    __shared__ __align__(16) float gl1[256], gl2[256];   // gate exchange (200 used;
                                                         // 200..255 garbage, masked)

    const int tid = threadIdx.x;           // 0..127
    const int wv  = tid >> 6;              // wave 0/1
    const int ln  = tid & 63;
    const int b   = blockIdx.x;
    const int predict = *predict_p;
    const int S = T + predict;

    for (int i = tid; i < TLEN; i += 128)
        x_lds[i] = x[(size_t)b * T + i];

    // ---- per-thread gate rows: rowA = tid, rowB = tid+128 (valid tid<72) ----
    const int rowA = tid;
    const bool hasB = (tid + 128 < 200);
    const int rowB = hasB ? (tid + 128) : 0;     // clamp; gB write is masked

    float wA1[Hh], wB1[Hh], wiA2[Hh], wiB2[Hh], whA2[Hh], whB2[Hh];
    const float wihA = W_ih1[rowA],  wihB = W_ih1[rowB];
    const float b1A  = b_ih1[rowA] + b_hh1[rowA];
    const float b1B  = b_ih1[rowB] + b_hh1[rowB];
    const float b2A  = b_ih2[rowA] + b_hh2[rowA];
    const float b2B  = b_ih2[rowB] + b_hh2[rowB];
    #pragma unroll
    for (int k = 0; k < Hh; ++k) {
        wA1[k]  = W_hh1[rowA * Hh + k];  wB1[k]  = W_hh1[rowB * Hh + k];
        wiA2[k] = W_ih2[rowA * Hh + k];  wiB2[k] = W_ih2[rowB * Hh + k];
        whA2[k] = W_hh2[rowA * Hh + k];  whB2[k] = W_hh2[rowB * Hh + k];
    }

    const float wlin_l = (ln < Hh) ? W_lin[ln] : 0.0f;
    const float blin   = b_lin[0];

    // spread state: lane u holds unit u's h/c (identical in both waves)
    float h1sp = 0.0f, h2sp = 0.0f, c1 = 0.0f, c2 = 0.0f;
    float o_reg = 0.0f;

    __syncthreads();
    float xin = x_lds[0];

    for (int s = 0; s < S; ++s) {
        // ======== G1: rows rowA,rowB; h1 via chunked readlane ========
        {
            float aA0 = b1A + xin * wihA, aA1 = 0.0f, aA2 = 0.0f, aA3 = 0.0f;
            float aB0 = b1B + xin * wihB, aB1 = 0.0f, aB2 = 0.0f, aB3 = 0.0f;
            CHUNK8(wA1, wB1, h1sp, 0);  CHUNK8(wA1, wB1, h1sp, 8);
            CHUNK8(wA1, wB1, h1sp, 16); CHUNK8(wA1, wB1, h1sp, 24);
            CHUNK8(wA1, wB1, h1sp, 32); CHUNK8(wA1, wB1, h1sp, 40);
            CHUNK2T(wA1, wB1, h1sp);
            gl1[tid] = (aA0 + aA2) + (aA1 + aA3);
            if (hasB) gl1[tid + 128] = (aB0 + aB2) + (aB1 + aB3);
        }
        __syncthreads();   // X1: gl1 complete
        // ======== U1 (redundant in both waves, unit = lane = ln) ========
        // direct LDS gather: i=gl[u], f=gl[50+u], g=gl[100+u], o=gl[150+u]
        // (consecutive per-lane addrs -> 2-way bank aliasing, free; lanes>=50
        //  read garbage at 200..213, masked below)
        {
            float gi = gl1[ln];
            float gf = gl1[Hh + ln];
            float gg = gl1[2 * Hh + ln];
            float go = gl1[3 * Hh + ln];
            float cn = fast_sigmoid(gf) * c1 + fast_sigmoid(gi) * fast_tanh(gg);
            c1 = cn;
            h1sp = (ln < Hh) ? fast_sigmoid(go) * fast_tanh(cn) : 0.0f;
        }

        // ======== G2: b2 + h1(cur)·Wi2 + h2(prv)·Wh2 (R5 sweep order) ========
        {
            float aA0 = b2A, aA1 = 0.0f, aA2 = 0.0f, aA3 = 0.0f;
            float aB0 = b2B, aB1 = 0.0f, aB2 = 0.0f, aB3 = 0.0f;
            CHUNK8(wiA2, wiB2, h1sp, 0);  CHUNK8(wiA2, wiB2, h1sp, 8);
            CHUNK8(wiA2, wiB2, h1sp, 16); CHUNK8(wiA2, wiB2, h1sp, 24);
            CHUNK8(wiA2, wiB2, h1sp, 32); CHUNK8(wiA2, wiB2, h1sp, 40);
            CHUNK2T(wiA2, wiB2, h1sp);
            CHUNK8(whA2, whB2, h2sp, 0);  CHUNK8(whA2, whB2, h2sp, 8);
            CHUNK8(whA2, whB2, h2sp, 16); CHUNK8(whA2, whB2, h2sp, 24);
            CHUNK8(whA2, whB2, h2sp, 32); CHUNK8(whA2, whB2, h2sp, 40);
            CHUNK2T(whA2, whB2, h2sp);
            gl2[tid] = (aA0 + aA2) + (aA1 + aA3);
            if (hasB) gl2[tid + 128] = (aB0 + aB2) + (aB1 + aB3);
        }
        __syncthreads();   // X2: gl2 complete

        // ---- wave1: deferred output for step s-1 (uses h2sp BEFORE U2) ----
        if (wv == 1 && s > 0 && s < T) {
            float part = (ln < Hh) ? h2sp * wlin_l : 0.0f;
            #pragma unroll
            for (int off = 32; off > 0; off >>= 1)
                part += __shfl_down(part, off);
            if (ln == 0) out[(size_t)b * S + (s - 1)] = part + blin;
        }

        // ======== U2 (redundant, unit = lane) ========
        {
            float gi = gl2[ln];
            float gf = gl2[Hh + ln];
            float gg = gl2[2 * Hh + ln];
            float go = gl2[3 * Hh + ln];
            float cn = fast_sigmoid(gf) * c2 + fast_sigmoid(gi) * fast_tanh(gg);
            c2 = cn;
            h2sp = (ln < Hh) ? fast_sigmoid(go) * fast_tanh(cn) : 0.0f;
        }

        // ======== transition + predict: o feeds next input (register-only) ====
        if (s >= T - 1) {
            float part = (ln < Hh) ? h2sp * wlin_l : 0.0f;
            #pragma unroll
            for (int off = 32; off > 0; off >>= 1)
                part += __shfl_down(part, off);
            float tot = __shfl(part, 0);        // both waves compute identically
            o_reg = tot + blin;
            if (wv == 1 && ln == 0) out[(size_t)b * S + s] = o_reg;
        }
        xin = (s + 1 < T) ? x_lds[s + 1] : o_reg;
        // Hazards: gl1 R(U1,s, X1..X2) vs W(G1,s+1, post-X2(s)): X2 separates.
        //          gl2 R(U2,s, post-X2) vs W(G2,s+1, post-X1(s+1)): X1 separates.
        //          h/c/o are per-wave registers (identical copies in both waves).
    }
}

extern "C" void kernel_launch(void* const* d_in, const int* in_sizes, int n_in,
                              void* d_out, int out_size, void* d_ws, size_t ws_size,
                              hipStream_t stream) {
    const float* x      = (const float*)d_in[0];
    const float* W_ih1  = (const float*)d_in[1];
    const float* W_hh1  = (const float*)d_in[2];
    const float* b_ih1  = (const float*)d_in[3];
    const float* b_hh1  = (const float*)d_in[4];
    const float* W_ih2  = (const float*)d_in[5];
    const float* W_hh2  = (const float*)d_in[6];
    const float* b_ih2  = (const float*)d_in[7];
    const float* b_hh2  = (const float*)d_in[8];
    const float* W_lin  = (const float*)d_in[9];
    const float* b_lin  = (const float*)d_in[10];
    const int*   pred   = (const int*)d_in[11];
    float* out = (float*)d_out;

    const int B = 512;                 // fixed by setup_inputs
    const int T = in_sizes[0] / B;     // 1024

    dim3 grid(B), block(128);
    hipLaunchKernelGGL(sine_lstm_kernel, grid, block, 0, stream,
                       x, W_ih1, W_hh1, b_ih1, b_hh1,
                       W_ih2, W_hh2, b_ih2, b_hh2,
                       W_lin, b_lin, pred, out, T);
}

// Round 8
// 1503.315 us; speedup vs baseline: 1.4044x; 1.4044x over previous
//
#include <hip/hip_runtime.h>

// SineLSTM: 2-layer LSTM (H=50), B=512 rows, one row per block.
// R10: R5's exact 3-barrier structure; h-broadcast + weights switched to
// packed f16 with v_dot2_f32_f16 (fp32 accumulate).
// Model (fits R2/R5/R6 within 2%): per-CU LDS broadcast pipe is the wall
// (312 b128/CU-step x 12cy = 3744cy = measured step). Delivery cost per
// h-VALUE is ~3cy on any pipe (readlane attempts R4/R9 were no better and
// burned VALU issue). f16 halves delivered bytes: 21 b128/wave-step
// (168/CU ~ 2000cy), halves FMA count (84 dot2), halves weight regs
// (84 half2 -> should stay architectural VGPR, killing the AGPR-read tax
// seen in R4/R7/R9).
// Precision: recurrence h/W in f16 (11-bit mantissa, ~2-4e-3 steady-state),
// c1/c2/gates/bias/x/output path all fp32 (wave1 recomputes activations in
// fp32 for the output dot). Threshold 6.09e-3, R5 was at 1.95e-3.

#define Hh   50
#define G4   200
#define TLEN 1024

typedef _Float16 half2v __attribute__((ext_vector_type(2)));

#if __has_builtin(__builtin_amdgcn_fdot2)
#define FDOT2(a, b, c) __builtin_amdgcn_fdot2((a), (b), (c), false)
#else
#define FDOT2(a, b, c) ((c) + (float)(a)[0] * (float)(b)[0] + (float)(a)[1] * (float)(b)[1])
#endif

__device__ __forceinline__ float fast_sigmoid(float v) {
    return 1.0f / (1.0f + __expf(-v));
}
__device__ __forceinline__ float fast_tanh(float v) {
    return 1.0f - 2.0f / (__expf(2.0f * v) + 1.0f);
}

extern "C" __global__ __launch_bounds__(256, 2)
void sine_lstm_kernel(const float* __restrict__ x,
                      const float* __restrict__ W_ih1,
                      const float* __restrict__ W_hh1,
                      const float* __restrict__ b_ih1,
                      const float* __restrict__ b_hh1,
                      const float* __restrict__ W_ih2,
                      const float* __restrict__ W_hh2,
                      const float* __restrict__ b_ih2,
                      const float* __restrict__ b_hh2,
                      const float* __restrict__ W_lin,
                      const float* __restrict__ b_lin,
                      const int*   __restrict__ predict_p,
                      float* __restrict__ out,
                      int T)
{
    __shared__ __align__(16) float x_lds[TLEN];
    __shared__ __align__(16) _Float16 h1h[64];    // f16 h1; [50..63] stay 0
    __shared__ __align__(16) _Float16 h2h[64];    // f16 h2
    __shared__ __align__(16) float c2v[64];
    __shared__ __align__(16) float g1b[G4], g2b[G4];   // fp32 gates, flat
    __shared__ float o_lds;

    const int tid = threadIdx.x;
    const int b   = blockIdx.x;
    const int predict = *predict_p;
    const int S = T + predict;

    for (int i = tid; i < TLEN; i += 256)
        x_lds[i] = x[(size_t)b * T + i];
    if (tid < 64) { h1h[tid] = (_Float16)0.0f; h2h[tid] = (_Float16)0.0f; c2v[tid] = 0.0f; }

    // ---- per-thread weight row, packed f16 pairs (28 pairs = 56 >= 50) ----
    const int j  = tid;
    const int jc = (j < G4) ? j : 0;        // clamp; stores are masked
    half2v w1p[28], wi2p[28], wh2p[28];
    const float wih1_j = W_ih1[jc];
    const float b1_j   = b_ih1[jc] + b_hh1[jc];
    const float b2_j   = b_ih2[jc] + b_hh2[jc];
    #pragma unroll
    for (int p = 0; p < 28; ++p) {
        const int k0 = 2 * p, k1 = 2 * p + 1;
        const float a0 = (k0 < Hh) ? W_hh1[jc * Hh + k0] : 0.0f;
        const float a1 = (k1 < Hh) ? W_hh1[jc * Hh + k1] : 0.0f;
        const float b0 = (k0 < Hh) ? W_ih2[jc * Hh + k0] : 0.0f;
        const float b1v = (k1 < Hh) ? W_ih2[jc * Hh + k1] : 0.0f;
        const float c0 = (k0 < Hh) ? W_hh2[jc * Hh + k0] : 0.0f;
        const float c1v = (k1 < Hh) ? W_hh2[jc * Hh + k1] : 0.0f;
        w1p[p]  = half2v{(_Float16)a0, (_Float16)a1};
        wi2p[p] = half2v{(_Float16)b0, (_Float16)b1v};
        wh2p[p] = half2v{(_Float16)c0, (_Float16)c1v};
    }

    const int wv = tid >> 6;
    const int ln = tid & 63;
    const float wlin_l = (ln < Hh) ? W_lin[ln] : 0.0f;
    const float blin   = b_lin[0];
    float c1r = 0.0f;                       // layer-1 cell: wave0-private

    __syncthreads();

    for (int s = 0; s < S; ++s) {
        // ======== G1: b1 + xin*W_ih1[j] + h1.W_hh1[j]  (f16 dot2) ========
        {
            float xin = (s < T) ? x_lds[s] : o_lds;
            float a0 = b1_j + xin * wih1_j, a1 = 0.0f, a2 = 0.0f, a3 = 0.0f;
            #pragma unroll
            for (int L = 0; L < 7; ++L) {
                float4 f = *(const float4*)&h1h[8 * L];    // ds_read_b128 broadcast
                a0 = FDOT2(w1p[4 * L + 0], __builtin_bit_cast(half2v, f.x), a0);
                a1 = FDOT2(w1p[4 * L + 1], __builtin_bit_cast(half2v, f.y), a1);
                a2 = FDOT2(w1p[4 * L + 2], __builtin_bit_cast(half2v, f.z), a2);
                a3 = FDOT2(w1p[4 * L + 3], __builtin_bit_cast(half2v, f.w), a3);
            }
            if (j < G4) g1b[j] = (a0 + a2) + (a1 + a3);
        }
        __syncthreads();   // B1: g1 complete

        // ======== U1: wave0 lanes<50 update layer-1 state (fp32) ========
        if (wv == 0 && ln < Hh) {
            float ig = g1b[ln], fg = g1b[ln + Hh], gg = g1b[ln + 2 * Hh], og = g1b[ln + 3 * Hh];
            float cn = fast_sigmoid(fg) * c1r + fast_sigmoid(ig) * fast_tanh(gg);
            c1r = cn;
            h1h[ln] = (_Float16)(fast_sigmoid(og) * fast_tanh(cn));
        }
        __syncthreads();   // B2: h1 complete

        float cp2 = 0.0f;
        if (wv == 1 && ln < Hh) cp2 = c2v[ln];   // c2 stable during G2

        // ======== G2: b2 + h1.W_ih2[j] + h2.W_hh2[j]  (f16 dot2) ========
        {
            float a0 = b2_j, a1 = 0.0f, a2 = 0.0f, a3 = 0.0f;
            #pragma unroll
            for (int L = 0; L < 7; ++L) {
                float4 f = *(const float4*)&h1h[8 * L];
                a0 = FDOT2(wi2p[4 * L + 0], __builtin_bit_cast(half2v, f.x), a0);
                a1 = FDOT2(wi2p[4 * L + 1], __builtin_bit_cast(half2v, f.y), a1);
                a2 = FDOT2(wi2p[4 * L + 2], __builtin_bit_cast(half2v, f.z), a2);
                a3 = FDOT2(wi2p[4 * L + 3], __builtin_bit_cast(half2v, f.w), a3);
            }
            #pragma unroll
            for (int L = 0; L < 7; ++L) {
                float4 f = *(const float4*)&h2h[8 * L];
                a0 = FDOT2(wh2p[4 * L + 0], __builtin_bit_cast(half2v, f.x), a0);
                a1 = FDOT2(wh2p[4 * L + 1], __builtin_bit_cast(half2v, f.y), a1);
                a2 = FDOT2(wh2p[4 * L + 2], __builtin_bit_cast(half2v, f.z), a2);
                a3 = FDOT2(wh2p[4 * L + 3], __builtin_bit_cast(half2v, f.w), a3);
            }
            if (j < G4) g2b[j] = (a0 + a2) + (a1 + a3);
        }
        __syncthreads();   // B3: g2 complete

        // ======== U2a: wave0 = layer-2 state update (fp32) ========
        if (wv == 0 && ln < Hh) {
            float ig = g2b[ln], fg = g2b[ln + Hh], gg = g2b[ln + 2 * Hh], og = g2b[ln + 3 * Hh];
            float c  = c2v[ln];
            float cn = fast_sigmoid(fg) * c + fast_sigmoid(ig) * fast_tanh(gg);
            c2v[ln] = cn;
            h2h[ln] = (_Float16)(fast_sigmoid(og) * fast_tanh(cn));
        }
        // ======== U2b: wave1 = output dot (redundant fp32 activations) ========
        if (wv == 1) {
            float part = 0.0f;
            if (ln < Hh) {
                float ig = g2b[ln], fg = g2b[ln + Hh], gg = g2b[ln + 2 * Hh], og = g2b[ln + 3 * Hh];
                float cn = fast_sigmoid(fg) * cp2 + fast_sigmoid(ig) * fast_tanh(gg);
                float hn = fast_sigmoid(og) * fast_tanh(cn);
                part = hn * wlin_l;
            }
            #pragma unroll
            for (int off = 32; off > 0; off >>= 1)
                part += __shfl_down(part, off);
            if (ln == 0) {
                float o = part + blin;
                out[(size_t)b * S + s] = o;
                o_lds = o;
            }
        }
        // B4 only needed once o_lds feeds next step's G1 (predict phase).
        // Hazard audit identical to R5 (h2h/c2v play h2_lds/c2v roles):
        //  g1 W(s+1) after U1-reads(s) via B2,B3; g2 W(s+1) after U2-reads(s)
        //  via B1,B2(s+1); h1 W(s+1) after G2-reads(s) via B3(s)+B1(s+1);
        //  h2/c2 W(s) before G2-reads(s+1) via B1+B2(s+1).
        if (s >= T - 1) __syncthreads();
    }
}

extern "C" void kernel_launch(void* const* d_in, const int* in_sizes, int n_in,
                              void* d_out, int out_size, void* d_ws, size_t ws_size,
                              hipStream_t stream) {
    const float* x      = (const float*)d_in[0];
    const float* W_ih1  = (const float*)d_in[1];
    const float* W_hh1  = (const float*)d_in[2];
    const float* b_ih1  = (const float*)d_in[3];
    const float* b_hh1  = (const float*)d_in[4];
    const float* W_ih2  = (const float*)d_in[5];
    const float* W_hh2  = (const float*)d_in[6];
    const float* b_ih2  = (const float*)d_in[7];
    const float* b_hh2  = (const float*)d_in[8];
    const float* W_lin  = (const float*)d_in[9];
    const float* b_lin  = (const float*)d_in[10];
    const int*   pred   = (const int*)d_in[11];
    float* out = (float*)d_out;

    const int B = 512;                 // fixed by setup_inputs
    const int T = in_sizes[0] / B;     // 1024

    dim3 grid(B), block(256);
    hipLaunchKernelGGL(sine_lstm_kernel, grid, block, 0, stream,
                       x, W_ih1, W_hh1, b_ih1, b_hh1,
                       W_ih2, W_hh2, b_ih2, b_hh2,
                       W_lin, b_lin, pred, out, T);
}